// Round 6
// baseline (2181.457 us; speedup 1.0000x reference)
//
#include <hip/hip_runtime.h>

#define T_LEN 2500
#define B_SZ  128
#define I_SZ  76
#define HID   32
#define G3    96   // 3*HID
#define CPW   4    // chains per wave (scan)
#define XG_BT 128  // (b,t) rows per block (xg)

// ---------------------------------------------------------------------------
// Kernel 1 (R5 rewrite): thread owns (dir, gate g); W row lives in registers;
// x rows read via wave-uniform addresses (scalarizable); no LDS, no barrier.
// grid: 2500 blocks x 192 threads. xg[dir][bt][g], bt = b*T_LEN + t.
// ---------------------------------------------------------------------------
__global__ __launch_bounds__(192) void xg_kernel(
    const float* __restrict__ X,
    const float* __restrict__ Wf, const float* __restrict__ bf,
    const float* __restrict__ Wb, const float* __restrict__ bb,
    float* __restrict__ xg)
{
    const int tid = threadIdx.x;        // 0..191
    const int dir = tid / G3;           // 0 or 1
    const int g   = tid - dir * G3;     // 0..95

    const float* W  = dir ? Wb : Wf;
    const float  bias = (dir ? bb : bf)[g];

    // W row g: 76 floats = 19 float4 (rows are 304B = 16B-aligned)
    float w[I_SZ];
    {
        const float4* wr = (const float4*)(W + (size_t)g * I_SZ);
        #pragma unroll
        for (int j = 0; j < I_SZ / 4; ++j) {
            float4 v = wr[j];
            w[4*j+0] = v.x; w[4*j+1] = v.y; w[4*j+2] = v.z; w[4*j+3] = v.w;
        }
    }

    const size_t bt0 = (size_t)blockIdx.x * XG_BT;
    const float* xrow = X + bt0 * I_SZ;                       // wave-uniform
    float* op = xg + (size_t)dir * B_SZ * T_LEN * G3 + bt0 * G3 + g;

    #pragma unroll 2
    for (int i = 0; i < XG_BT; ++i) {
        const float4* xv4 = (const float4*)(xrow + (size_t)i * I_SZ); // uniform addr
        float acc = bias;
        #pragma unroll
        for (int j = 0; j < I_SZ / 4; ++j) {
            float4 xv = xv4[j];
            acc = fmaf(xv.x, w[4*j+0], acc);
            acc = fmaf(xv.y, w[4*j+1], acc);
            acc = fmaf(xv.z, w[4*j+2], acc);
            acc = fmaf(xv.w, w[4*j+3], acc);
        }
        op[(size_t)i * G3] = acc;   // threads g=0..95 per dir: coalesced 384B
    }
}

// ---------------------------------------------------------------------------
// Kernel 2 (R5): 4 independent same-direction chains per wave. Per-chain math
// is exactly R2's verified structure (K-split dots, permlane32 combine, LDS
// h-broadcast, branchless clamped prefetch) + R4's verified clamp-free tanh.
// Dots interleaved across chains (j outer, c inner) to keep issue flowing.
// lane l: k = l&31 (hidden index), kh = l>>5 (K-half).
// grid: 64 blocks x 64 threads; block = dir*32 + bq, chains b = bq*4+c.
// ---------------------------------------------------------------------------
__global__ __launch_bounds__(64) void scan_kernel(
    const float* __restrict__ xg,
    const float* __restrict__ Whf, const float* __restrict__ bhf,
    const float* __restrict__ Whb, const float* __restrict__ bhb,
    float* __restrict__ out)
{
    __shared__ __align__(16) float hsh[CPW][HID];

    const int l  = threadIdx.x;
    const int k  = l & 31;
    const int kh = l >> 5;
    const int dir = blockIdx.x >> 5;   // 0..31 fwd, 32..63 bwd
    const int bq  = blockIdx.x & 31;

    const float* Wh = dir ? Whb : Whf;
    const float* bh = dir ? bhb : bhf;

    // per-lane W_hh fragments: rows {k, 32+k, 64+k}, cols [kh*16, kh*16+16)
    float wr[16], wz[16], wn[16];
    {
        const float4* q;
        q = (const float4*)(Wh + (0*HID + k) * HID + kh * 16);
        #pragma unroll
        for (int i = 0; i < 4; ++i) { float4 v = q[i];
            wr[4*i+0]=v.x; wr[4*i+1]=v.y; wr[4*i+2]=v.z; wr[4*i+3]=v.w; }
        q = (const float4*)(Wh + (1*HID + k) * HID + kh * 16);
        #pragma unroll
        for (int i = 0; i < 4; ++i) { float4 v = q[i];
            wz[4*i+0]=v.x; wz[4*i+1]=v.y; wz[4*i+2]=v.z; wz[4*i+3]=v.w; }
        q = (const float4*)(Wh + (2*HID + k) * HID + kh * 16);
        #pragma unroll
        for (int i = 0; i < 4; ++i) { float4 v = q[i];
            wn[4*i+0]=v.x; wn[4*i+1]=v.y; wn[4*i+2]=v.z; wn[4*i+3]=v.w; }
    }
    // half-bias trick: both K-halves contribute bias*0.5, combine sums to 1x
    const float bhr = 0.5f * bh[k];
    const float bhz = 0.5f * bh[32 + k];
    const float bhn = 0.5f * bh[64 + k];

    const int step = dir ? -G3 : G3;
    const float* xb[CPW];
    #pragma unroll
    for (int c = 0; c < CPW; ++c) {
        const int p = dir * 128 + bq * CPW + c;
        xb[c] = xg + ((size_t)p * T_LEN + (dir ? (T_LEN - 1) : 0)) * G3;
    }

    float hh[CPW][16];
    float hk[CPW];
    #pragma unroll
    for (int c = 0; c < CPW; ++c) {
        hk[c] = 0.f;
        #pragma unroll
        for (int j = 0; j < 16; ++j) hh[c][j] = 0.f;
    }

    // 4-deep prefetch ring per chain (all indices compile-time)
    float px[CPW][4], py[CPW][4], pz[CPW][4];
    #pragma unroll
    for (int c = 0; c < CPW; ++c)
        #pragma unroll
        for (int d = 0; d < 4; ++d) {
            const float* q = xb[c] + (long)d * step;
            px[c][d] = q[k]; py[c][d] = q[32 + k]; pz[c][d] = q[64 + k];
        }

    #pragma unroll 4
    for (int t = 0; t < T_LEN; ++t) {
        const int slot = t & 3;

        // consume + branchless clamped prefetch (issued early, off-chain)
        float xr[CPW], xz[CPW], xn[CPW];
        #pragma unroll
        for (int c = 0; c < CPW; ++c) {
            xr[c] = px[c][slot]; xz[c] = py[c][slot]; xn[c] = pz[c][slot];
        }
        {
            const int tp = (t + 4 < T_LEN) ? (t + 4) : (T_LEN - 1);
            #pragma unroll
            for (int c = 0; c < CPW; ++c) {
                const float* q = xb[c] + (long)tp * step;
                px[c][slot] = q[k]; py[c][slot] = q[32 + k]; pz[c][slot] = q[64 + k];
            }
        }

        // K-split partial dots, interleaved across chains (12 indep streams)
        float hr[CPW], hz[CPW], hn[CPW];
        #pragma unroll
        for (int c = 0; c < CPW; ++c) { hr[c] = bhr; hz[c] = bhz; hn[c] = bhn; }
        #pragma unroll
        for (int j = 0; j < 16; ++j) {
            #pragma unroll
            for (int c = 0; c < CPW; ++c) {
                hr[c] = fmaf(wr[j], hh[c][j], hr[c]);
                hz[c] = fmaf(wz[j], hh[c][j], hz[c]);
                hn[c] = fmaf(wn[j], hh[c][j], hn[c]);
            }
        }
        // combine K-halves via VALU permlane swap (R2-verified pattern)
        #pragma unroll
        for (int c = 0; c < CPW; ++c) {
            float a0 = hr[c], a1 = hr[c];
            asm("v_permlane32_swap_b32 %0, %1" : "+v"(a0), "+v"(a1));
            hr[c] = a0 + a1;
            float b0 = hz[c], b1 = hz[c];
            asm("v_permlane32_swap_b32 %0, %1" : "+v"(b0), "+v"(b1));
            hz[c] = b0 + b1;
            float c0 = hn[c], c1 = hn[c];
            asm("v_permlane32_swap_b32 %0, %1" : "+v"(c0), "+v"(c1));
            hn[c] = c0 + c1;
        }

        // gates (all 64 lanes hold full sums -> identical results both halves)
        #pragma unroll
        for (int c = 0; c < CPW; ++c) {
            const float r = __builtin_amdgcn_rcpf(1.f +
                __builtin_amdgcn_exp2f(-1.442695040888963f * (xr[c] + hr[c])));
            const float z = __builtin_amdgcn_rcpf(1.f +
                __builtin_amdgcn_exp2f(-1.442695040888963f * (xz[c] + hz[c])));
            const float qx  = 2.885390081777927f * xn[c];
            const float q2v = 2.885390081777927f * hn[c];
            const float E   = __builtin_amdgcn_exp2f(fmaf(r, q2v, qx));
            const float n   = fmaf(-2.f, __builtin_amdgcn_rcpf(E + 1.f), 1.f);
            hk[c] = fmaf(z, hk[c] - n, n);
        }

        // h-broadcast: both halves write identical values (benign same-addr),
        // single-wave block -> in-order LDS pipe, no barrier
        #pragma unroll
        for (int c = 0; c < CPW; ++c) hsh[c][k] = hk[c];
        #pragma unroll
        for (int c = 0; c < CPW; ++c) {
            const float4* hv = (const float4*)(&hsh[c][kh * 16]);
            float4 h0 = hv[0], h1 = hv[1], h2 = hv[2], h3 = hv[3];
            hh[c][ 0]=h0.x; hh[c][ 1]=h0.y; hh[c][ 2]=h0.z; hh[c][ 3]=h0.w;
            hh[c][ 4]=h1.x; hh[c][ 5]=h1.y; hh[c][ 6]=h1.z; hh[c][ 7]=h1.w;
            hh[c][ 8]=h2.x; hh[c][ 9]=h2.y; hh[c][10]=h2.z; hh[c][11]=h2.w;
            hh[c][12]=h3.x; hh[c][13]=h3.y; hh[c][14]=h3.z; hh[c][15]=h3.w;
        }
    }

    // output: (B, 2, H)
    if (l < 32) {
        #pragma unroll
        for (int c = 0; c < CPW; ++c) {
            const int b = bq * CPW + c;
            out[(b * 2 + dir) * HID + k] = hk[c];
        }
    }
}

extern "C" void kernel_launch(void* const* d_in, const int* in_sizes, int n_in,
                              void* d_out, int out_size, void* d_ws, size_t ws_size,
                              hipStream_t stream) {
    const float* X    = (const float*)d_in[0];
    const float* Wihf = (const float*)d_in[1];
    const float* Whhf = (const float*)d_in[2];
    const float* bihf = (const float*)d_in[3];
    const float* bhhf = (const float*)d_in[4];
    const float* Wihb = (const float*)d_in[5];
    const float* Whhb = (const float*)d_in[6];
    const float* bihb = (const float*)d_in[7];
    const float* bhhb = (const float*)d_in[8];
    float* out = (float*)d_out;
    float* xg  = (float*)d_ws;

    const size_t needed = (size_t)2 * B_SZ * T_LEN * G3 * sizeof(float); // 245.76 MB
    if (ws_size < needed) return;

    xg_kernel<<<(B_SZ * T_LEN) / XG_BT, 192, 0, stream>>>(X, Wihf, bihf, Wihb, bihb, xg);
    scan_kernel<<<64, 64, 0, stream>>>(xg, Whhf, bhhf, Whhb, bhhb, out);
}

// Round 9
// 839.981 us; speedup vs baseline: 2.5970x; 2.5970x over previous
//
#include <hip/hip_runtime.h>

#define T_LEN 2500
#define B_SZ  128
#define I_SZ  76
#define HID   32
#define G3    96   // 3*HID
#define PFD   4    // prefetch ring depth (divides T_LEN)

// ---------------------------------------------------------------------------
// DPP helper: row-rotate within 16-lane rows (all-VALU cross-lane)
// ---------------------------------------------------------------------------
template<int CTRL>
__device__ __forceinline__ float dppf(float x) {
    return __builtin_bit_cast(float,
        __builtin_amdgcn_mov_dpp(__builtin_bit_cast(int, x), CTRL, 0xF, 0xF, true));
}

// ---------------------------------------------------------------------------
// Kernel 1 (unchanged from R7; R6/R7 cross-validation implies correct):
// xg[dir][bt][g] = X[bt,:]*W^T + b. Block: 64 bt-rows; 256 threads =
// 16 tx (strided rows {tx,tx+16,tx+32,tx+48}) x 16 ty (gate quads); 3 passes.
// grid: 5000 blocks x 256 threads.
// ---------------------------------------------------------------------------
__global__ __launch_bounds__(256) void xg_kernel(
    const float* __restrict__ X,
    const float* __restrict__ Wf, const float* __restrict__ bf,
    const float* __restrict__ Wb, const float* __restrict__ bb,
    float* __restrict__ xg)
{
    __shared__ __align__(16) float xs[64 * I_SZ];   // 19456 B, stride 76
    const int tid = threadIdx.x;
    const size_t bt0 = (size_t)blockIdx.x * 64;

    // coalesced staging: 64 rows x 19 float4 = 1216 float4, contiguous
    {
        const float4* src = (const float4*)(X + bt0 * I_SZ);
        float4* dst = (float4*)xs;
        #pragma unroll
        for (int i = 0; i < 4; ++i) dst[tid + 256 * i] = src[tid + 256 * i];
        if (tid < 192) dst[tid + 1024] = src[tid + 1024];
    }
    __syncthreads();

    const int tx = tid & 15;
    const int ty = tid >> 4;

    #pragma unroll 1
    for (int pass = 0; pass < 3; ++pass) {
        const int gb  = pass * 64 + ty * 4;     // 0..188, multiple of 4
        const int dir = gb >= G3;
        const int gg  = gb - dir * G3;          // 0..92
        const float* W  = dir ? Wb : Wf;
        const float* bs = dir ? bb : bf;

        float acc[4][4];                        // [row i][gate jj]
        #pragma unroll
        for (int jj = 0; jj < 4; ++jj) {
            const float bv = bs[gg + jj];
            #pragma unroll
            for (int i = 0; i < 4; ++i) acc[i][jj] = bv;
        }

        for (int kk = 0; kk < 19; ++kk) {
            float4 wv[4], xv[4];
            #pragma unroll
            for (int jj = 0; jj < 4; ++jj)
                wv[jj] = ((const float4*)(W + (size_t)(gg + jj) * I_SZ))[kk];
            #pragma unroll
            for (int i = 0; i < 4; ++i)
                xv[i] = ((const float4*)(xs + (size_t)(tx + 16 * i) * I_SZ))[kk];
            #pragma unroll
            for (int i = 0; i < 4; ++i)
                #pragma unroll
                for (int jj = 0; jj < 4; ++jj) {
                    acc[i][jj] = fmaf(xv[i].x, wv[jj].x, acc[i][jj]);
                    acc[i][jj] = fmaf(xv[i].y, wv[jj].y, acc[i][jj]);
                    acc[i][jj] = fmaf(xv[i].z, wv[jj].z, acc[i][jj]);
                    acc[i][jj] = fmaf(xv[i].w, wv[jj].w, acc[i][jj]);
                }
        }

        #pragma unroll
        for (int i = 0; i < 4; ++i) {
            float4 o; o.x = acc[i][0]; o.y = acc[i][1]; o.z = acc[i][2]; o.w = acc[i][3];
            *(float4*)(xg + ((size_t)dir * B_SZ * T_LEN + bt0 + tx + 16 * i) * G3 + gg) = o;
        }
    }
}

// ---------------------------------------------------------------------------
// Kernel 2 (R8): GRU scan, one wave per (b,dir).
// Layout: k=l&31 (owned h), j=l&15, kh=l>>5 (col-half), row=l>>4.
// Rows 0,1 dot cols [0:16); rows 2,3 dot cols [16:32); combine via
// permlane32_swap (ANTI-ALIASED asm). After gates lane l holds h_{l&31};
// rows 1,2 need the other 16 h's -> __shfl_xor(hk,16) (no asm, no aliasing).
// Then 15 mov_dpp row-rotations allgather; W pre-permuted by probed d.
// grid: 256 blocks x 64 threads.
// ---------------------------------------------------------------------------
__global__ __launch_bounds__(64) void scan_kernel(
    const float* __restrict__ xg,
    const float* __restrict__ Whf, const float* __restrict__ bhf,
    const float* __restrict__ Whb, const float* __restrict__ bhb,
    float* __restrict__ out)
{
    const int l   = threadIdx.x;
    const int k   = l & 31;
    const int j   = l & 15;
    const int kh  = l >> 5;
    const int row = l >> 4;
    const int p   = blockIdx.x;
    const int dir = p >> 7;
    const int b   = p & 127;

    const float* Wh = dir ? Whb : Whf;
    const float* bh = dir ? bhb : bhf;

    // DPP row_ror:1 receive-offset d (self-calibrating): lane j <- (j+d)&15
    const int d = (__builtin_amdgcn_mov_dpp(l, 0x121, 0xF, 0xF, true) - l) & 15;
    const bool needswap = (row == 1) || (row == 2);

    // W fragments, column-permuted to allgather slot order:
    // slot m holds h_{kh*16 + ((j + d*m)&15)}
    float wr[16], wz[16], wn[16];
    #pragma unroll
    for (int m = 0; m < 16; ++m) {
        const int col = kh * 16 + ((j + d * m) & 15);
        wr[m] = Wh[(0 * HID + k) * HID + col];
        wz[m] = Wh[(1 * HID + k) * HID + col];
        wn[m] = Wh[(2 * HID + k) * HID + col];
    }
    // half-bias trick: each col-half contributes 0.5x, combine sums to 1x
    const float bhr = 0.5f * bh[k];
    const float bhz = 0.5f * bh[32 + k];
    const float bhn = 0.5f * bh[64 + k];

    const float* xbase = xg + ((size_t)p * T_LEN + (dir ? (T_LEN - 1) : 0)) * G3;
    const int step = dir ? -G3 : G3;

    float g[16];
    #pragma unroll
    for (int m = 0; m < 16; ++m) g[m] = 0.f;   // h0 = 0
    float hk = 0.f;

    // prefetch ring
    float px[PFD], py[PFD], pz[PFD];
    #pragma unroll
    for (int dd = 0; dd < PFD; ++dd) {
        const float* q = xbase + (long)dd * step;
        px[dd] = q[k]; py[dd] = q[32 + k]; pz[dd] = q[64 + k];
    }

    #pragma unroll PFD
    for (int t = 0; t < T_LEN; ++t) {
        const int slot = t & (PFD - 1);
        const float xr = px[slot], xz = py[slot], xn = pz[slot];
        {   // branchless clamped prefetch (off-chain)
            const int tp = (t + PFD < T_LEN) ? (t + PFD) : (T_LEN - 1);
            const float* q = xbase + (long)tp * step;
            px[slot] = q[k]; py[slot] = q[32 + k]; pz[slot] = q[64 + k];
        }

        // col-half partial dots over the 16 gathered slots
        float hr = bhr, hz = bhz, hn = bhn;
        #pragma unroll
        for (int m = 0; m < 16; ++m) {
            hr = fmaf(wr[m], g[m], hr);
            hz = fmaf(wz[m], g[m], hz);
            hn = fmaf(wn[m], g[m], hn);
        }
        // combine col-halves with partner l^32. ANTI-ALIAS: opaque-touch a1
        // so the allocator can never coalesce the two swap operands.
        {
            float a0 = hr, a1 = hr;
            asm("" : "+v"(a1));
            asm("v_permlane32_swap_b32 %0, %1" : "+v"(a0), "+v"(a1));
            hr = a0 + a1;
            float b0 = hz, b1 = hz;
            asm("" : "+v"(b1));
            asm("v_permlane32_swap_b32 %0, %1" : "+v"(b0), "+v"(b1));
            hz = b0 + b1;
            float c0 = hn, c1 = hn;
            asm("" : "+v"(c1));
            asm("v_permlane32_swap_b32 %0, %1" : "+v"(c0), "+v"(c1));
            hn = c0 + c1;
        }

        // gates (R2-verified math, clamp-free tanh)
        const float r = __builtin_amdgcn_rcpf(1.f +
            __builtin_amdgcn_exp2f(-1.442695040888963f * (xr + hr)));
        const float z = __builtin_amdgcn_rcpf(1.f +
            __builtin_amdgcn_exp2f(-1.442695040888963f * (xz + hz)));
        const float qx  = 2.885390081777927f * xn;
        const float q2v = 2.885390081777927f * hn;
        const float E   = __builtin_amdgcn_exp2f(fmaf(r, q2v, qx));
        const float n   = fmaf(-2.f, __builtin_amdgcn_rcpf(E + 1.f), 1.f);
        hk = fmaf(z, hk - n, n);

        // redistribute h: rows 1,2 take their XOR-16 partner's value
        // (__shfl_xor: compiler-generated, aliasing-impossible)
        const float swp = __shfl_xor(hk, 16, 64);
        const float hb  = needswap ? swp : hk;
        // intra-row allgather: 4 doubling rounds of row_ror
        g[0] = hb;
        g[1] = dppf<0x121>(g[0]);
        g[2] = dppf<0x122>(g[0]);
        g[3] = dppf<0x122>(g[1]);
        g[4] = dppf<0x124>(g[0]);
        g[5] = dppf<0x124>(g[1]);
        g[6] = dppf<0x124>(g[2]);
        g[7] = dppf<0x124>(g[3]);
        g[8]  = dppf<0x128>(g[0]);
        g[9]  = dppf<0x128>(g[1]);
        g[10] = dppf<0x128>(g[2]);
        g[11] = dppf<0x128>(g[3]);
        g[12] = dppf<0x128>(g[4]);
        g[13] = dppf<0x128>(g[5]);
        g[14] = dppf<0x128>(g[6]);
        g[15] = dppf<0x128>(g[7]);
    }

    // output: (B, 2, H); lanes 0..31 hold h_k, k = l
    if (l < 32) out[(b * 2 + dir) * HID + k] = hk;
}

extern "C" void kernel_launch(void* const* d_in, const int* in_sizes, int n_in,
                              void* d_out, int out_size, void* d_ws, size_t ws_size,
                              hipStream_t stream) {
    const float* X    = (const float*)d_in[0];
    const float* Wihf = (const float*)d_in[1];
    const float* Whhf = (const float*)d_in[2];
    const float* bihf = (const float*)d_in[3];
    const float* bhhf = (const float*)d_in[4];
    const float* Wihb = (const float*)d_in[5];
    const float* Whhb = (const float*)d_in[6];
    const float* bihb = (const float*)d_in[7];
    const float* bhhb = (const float*)d_in[8];
    float* out = (float*)d_out;
    float* xg  = (float*)d_ws;

    const size_t xg_bytes = (size_t)2 * B_SZ * T_LEN * G3 * sizeof(float); // 245.76 MB
    if (ws_size < xg_bytes) return;

    xg_kernel<<<(B_SZ * T_LEN) / 64, 256, 0, stream>>>(X, Wihf, bihf, Wihb, bihb, xg);
    scan_kernel<<<256, 64, 0, stream>>>(xg, Whhf, bhhf, Whhb, bhhb, out);
}